// Round 1
// baseline (5890.718 us; speedup 1.0000x reference)
//
#include <hip/hip_runtime.h>
#include <hip/hip_bf16.h>
#include <cstdint>
#include <cstddef>

// Problem constants
#define BB 4
#define NN 4096
#define MM 16
#define CC 256
#define TOK (BB*NN)        // 16384 (b,n) pairs
#define SAMP (TOK*MM)      // 262144 neighbour tokens
#define EPSV 1e-5f

// ws layout (float offsets within first 16KB stats block)
#define F_A_DM 32
#define F_C_DM 288
#define F_A_DB 544
#define F_C_DB 800
#define F_WESUM 1056
#define F_WESQ 1312
#define F_A_WE 1568
#define F_C_WE 1824
// byte offsets
#define WS_Q_OFF 16384                         // float q[TOK*CC]   (16.78 MB)
#define WS_PSUM_OFF (WS_Q_OFF + TOK*CC*4)      // float psum[TOK*CC]
#define WS_PSQ_OFF (WS_PSUM_OFF + TOK*CC*4)    // float psq[TOK*CC]

// ---------------------------------------------------------------------------
// Kernel 1: global moments of diff = p - nb  (9 sums) for analytic BN stats
// ---------------------------------------------------------------------------
__global__ __launch_bounds__(256) void k_diff_stats(
    const float* __restrict__ pxyz, const float* __restrict__ nxyz,
    double* __restrict__ dst)
{
    int tid = blockIdx.x * 256 + threadIdx.x;
    int stride = gridDim.x * 256;
    float s[9];
#pragma unroll
    for (int j = 0; j < 9; ++j) s[j] = 0.f;
    for (int idx = tid; idx < SAMP; idx += stride) {
        int t = idx >> 4;
        float dx = pxyz[t*3+0] - nxyz[idx*3+0];
        float dy = pxyz[t*3+1] - nxyz[idx*3+1];
        float dz = pxyz[t*3+2] - nxyz[idx*3+2];
        s[0]+=dx; s[1]+=dy; s[2]+=dz;
        s[3]+=dx*dx; s[4]+=dx*dy; s[5]+=dx*dz;
        s[6]+=dy*dy; s[7]+=dy*dz; s[8]+=dz*dz;
    }
#pragma unroll
    for (int off = 32; off >= 1; off >>= 1) {
#pragma unroll
        for (int j = 0; j < 9; ++j) s[j] += __shfl_down(s[j], off, 64);
    }
    if ((threadIdx.x & 63) == 0) {
#pragma unroll
        for (int j = 0; j < 9; ++j) atomicAdd(&dst[j], (double)s[j]);
    }
}

// ---------------------------------------------------------------------------
// Kernel 2: per-channel analytic BN scale/shift for dm and db paths
// ---------------------------------------------------------------------------
__global__ void k_finalize_dmdb(
    const double* __restrict__ mom,
    const float* __restrict__ mw1, const float* __restrict__ mb1,
    const float* __restrict__ mg,  const float* __restrict__ mbe,
    const float* __restrict__ bw1, const float* __restrict__ bb1,
    const float* __restrict__ bg,  const float* __restrict__ bbe,
    float* __restrict__ wsf)
{
    int c = threadIdx.x;
    double inv = 1.0 / (double)SAMP;
    double Ex = mom[0]*inv, Ey = mom[1]*inv, Ez = mom[2]*inv;
    double Cxx = mom[3]*inv - Ex*Ex, Cxy = mom[4]*inv - Ex*Ey, Cxz = mom[5]*inv - Ex*Ez;
    double Cyy = mom[6]*inv - Ey*Ey, Cyz = mom[7]*inv - Ey*Ez, Czz = mom[8]*inv - Ez*Ez;
    {
        double w0 = mw1[c*3+0], w1 = mw1[c*3+1], w2 = mw1[c*3+2];
        double mu = w0*Ex + w1*Ey + w2*Ez + (double)mb1[c];
        double var = w0*w0*Cxx + w1*w1*Cyy + w2*w2*Czz
                   + 2.0*(w0*w1*Cxy + w0*w2*Cxz + w1*w2*Cyz);
        float a = mg[c] * rsqrtf((float)var + EPSV);
        wsf[F_A_DM + c] = a;
        wsf[F_C_DM + c] = mbe[c] - (float)mu * a;
    }
    {
        double w0 = bw1[c*3+0], w1 = bw1[c*3+1], w2 = bw1[c*3+2];
        double mu = w0*Ex + w1*Ey + w2*Ez + (double)bb1[c];
        double var = w0*w0*Cxx + w1*w1*Cyy + w2*w2*Czz
                   + 2.0*(w0*w1*Cxy + w0*w2*Cxz + w1*w2*Cyz);
        float a = bg[c] * rsqrtf((float)var + EPSV);
        wsf[F_A_DB + c] = a;
        wsf[F_C_DB + c] = bbe[c] - (float)mu * a;
    }
}

// ---------------------------------------------------------------------------
// Kernel 3: q = points_features @ q_w^T + q_b  (16384 x 256) x (256 x 256)
// ---------------------------------------------------------------------------
__global__ __launch_bounds__(256) void k_q(
    const float* __restrict__ pf, const float* __restrict__ qw,
    const float* __restrict__ qb, float* __restrict__ qout)
{
    __shared__ float xs[8][CC];
    int t0 = blockIdx.x * 8;
    const float4* src = (const float4*)(pf + (size_t)t0 * CC);
    float4* dst = (float4*)&xs[0][0];
#pragma unroll
    for (int k = 0; k < 2; ++k) dst[threadIdx.x + 256*k] = src[threadIdx.x + 256*k];
    __syncthreads();
    int o = threadIdx.x;
    float acc[8];
#pragma unroll
    for (int t = 0; t < 8; ++t) acc[t] = 0.f;
    const float4* wrow = (const float4*)(qw + (size_t)o * CC);
    for (int i4 = 0; i4 < 64; ++i4) {
        float4 w = wrow[i4];
#pragma unroll
        for (int t = 0; t < 8; ++t) {
            float4 x = *(const float4*)&xs[t][i4*4];
            acc[t] += x.x*w.x + x.y*w.y + x.z*w.z + x.w*w.w;
        }
    }
    float bo = qb[o];
#pragma unroll
    for (int t = 0; t < 8; ++t) qout[(size_t)(t0+t)*CC + o] = acc[t] + bo;
}

// ---------------------------------------------------------------------------
// Kernel 4: main fused kernel, one block per (b,n) pair.
//  - h_dm/h_db from analytic-BN'd first linear
//  - k,v,dm,db GEMVs (16 tokens x 256 ch, K=256)
//  - va, grouped conv, softmax(32), we = omega * v
//  - writes we (fp32) into d_out (used as scratch), partial BN sums to ws
// ---------------------------------------------------------------------------
__global__ __launch_bounds__(256) void k_main(
    const float* __restrict__ pxyz, const float* __restrict__ nxyz,
    const float* __restrict__ nf,
    const float* __restrict__ mw1, const float* __restrict__ mb1,
    const float* __restrict__ mw2, const float* __restrict__ mb2,
    const float* __restrict__ bw1, const float* __restrict__ bb1,
    const float* __restrict__ bw2, const float* __restrict__ bb2,
    const float* __restrict__ kw,  const float* __restrict__ kbv,
    const float* __restrict__ vw,  const float* __restrict__ vbv,
    const float* __restrict__ convw,
    const float* __restrict__ wsf, const float* __restrict__ qws,
    float* __restrict__ weout,
    float* __restrict__ psum, float* __restrict__ psq)
{
    __shared__ float xs[MM][CC];
    __shared__ float hm[MM][CC];   // h_dm, later reused for va
    __shared__ float hb[MM][CC];
    __shared__ float omg[MM][32];
    __shared__ float dif[MM][4];

    int t = blockIdx.x;
    int c = threadIdx.x;

    // stage neighbour features (16x256 fp32 = 16KB)
    {
        const float4* src = (const float4*)(nf + (size_t)t * MM * CC);
        float4* dst = (float4*)&xs[0][0];
#pragma unroll
        for (int k = 0; k < 4; ++k) dst[c + 256*k] = src[c + 256*k];
    }
    if (c < MM) {
        float px = pxyz[t*3+0], py = pxyz[t*3+1], pz = pxyz[t*3+2];
        const float* nx = nxyz + ((size_t)t * MM + c) * 3;
        dif[c][0] = px - nx[0]; dif[c][1] = py - nx[1]; dif[c][2] = pz - nx[2];
    }
    __syncthreads();

    // h_dm / h_db: relu(BN(w1 . d + b1)) via precomputed scale/shift
    {
        float w0 = mw1[c*3+0], w1 = mw1[c*3+1], w2 = mw1[c*3+2], b1 = mb1[c];
        float am = wsf[F_A_DM + c], sm = wsf[F_C_DM + c];
        float u0 = bw1[c*3+0], u1 = bw1[c*3+1], u2 = bw1[c*3+2], b2 = bb1[c];
        float ab = wsf[F_A_DB + c], sb = wsf[F_C_DB + c];
#pragma unroll
        for (int m = 0; m < MM; ++m) {
            float d0 = dif[m][0], d1 = dif[m][1], d2 = dif[m][2];
            float h1 = w0*d0 + w1*d1 + w2*d2 + b1;
            hm[m][c] = fmaxf(0.f, h1*am + sm);
            float h2 = u0*d0 + u1*d1 + u2*d2 + b2;
            hb[m][c] = fmaxf(0.f, h2*ab + sb);
        }
    }
    __syncthreads();

    // GEMV: thread c computes channel c of k, v, dm, db for all 16 tokens
    float kacc[MM], vacc[MM], macc[MM], bacc[MM];
#pragma unroll
    for (int m = 0; m < MM; ++m) { kacc[m]=0.f; vacc[m]=0.f; macc[m]=0.f; bacc[m]=0.f; }
    {
        const float4* wkr = (const float4*)(kw  + (size_t)c * CC);
        const float4* wvr = (const float4*)(vw  + (size_t)c * CC);
        const float4* wmr = (const float4*)(mw2 + (size_t)c * CC);
        const float4* wbr = (const float4*)(bw2 + (size_t)c * CC);
        for (int i4 = 0; i4 < 64; ++i4) {
            float4 wk = wkr[i4], wv = wvr[i4], wm = wmr[i4], wb = wbr[i4];
#pragma unroll
            for (int m = 0; m < MM; ++m) {
                float4 x  = *(const float4*)&xs[m][i4*4];
                kacc[m] += x.x*wk.x + x.y*wk.y + x.z*wk.z + x.w*wk.w;
                vacc[m] += x.x*wv.x + x.y*wv.y + x.z*wv.z + x.w*wv.w;
                float4 h1 = *(const float4*)&hm[m][i4*4];
                macc[m] += h1.x*wm.x + h1.y*wm.y + h1.z*wm.z + h1.w*wm.w;
                float4 h2 = *(const float4*)&hb[m][i4*4];
                bacc[m] += h2.x*wb.x + h2.y*wb.y + h2.z*wb.z + h2.w*wb.w;
            }
        }
    }
    float qc = qws[(size_t)t * CC + c];
    float kb_ = kbv[c], vb_ = vbv[c], mb_ = mb2[c], bb_ = bb2[c];
    __syncthreads();   // done reading hm/hb; safe to overwrite hm with va

    float vreg[MM];
#pragma unroll
    for (int m = 0; m < MM; ++m) {
        float kk = kacc[m] + kb_;
        float vv = vacc[m] + vb_;
        vreg[m] = vv;
        float dmv = macc[m] + mb_;
        float dbv = bacc[m] + bb_;
        hm[m][c] = dmv * (qc - kk) + dbv;   // va
    }
    __syncthreads();

    // grouped conv: omega[m][o] = sum_j va[m][g*32+j] * conv_w[g][o&3][j], o=g*4+(o&3)
#pragma unroll
    for (int r = 0; r < 2; ++r) {
        int idx = c + r*256;
        int m = idx >> 5, o = idx & 31;
        int g = o >> 2;
        const float4* cw = (const float4*)(convw + (size_t)o * 32);
        const float4* va4 = (const float4*)&hm[m][g * 32];
        float s = 0.f;
#pragma unroll
        for (int j = 0; j < 8; ++j) {
            float4 a = va4[j]; float4 w = cw[j];
            s += a.x*w.x + a.y*w.y + a.z*w.z + a.w*w.w;
        }
        omg[m][o] = s;
    }
    __syncthreads();

    // softmax over the 32 outputs, per token (16 threads, serial 32 — tiny)
    if (c < MM) {
        float mx = -1e30f;
#pragma unroll
        for (int o = 0; o < 32; ++o) mx = fmaxf(mx, omg[c][o]);
        float s = 0.f;
#pragma unroll
        for (int o = 0; o < 32; ++o) { float e = __expf(omg[c][o] - mx); omg[c][o] = e; s += e; }
        float inv = 1.f / s;
#pragma unroll
        for (int o = 0; o < 32; ++o) omg[c][o] *= inv;
    }
    __syncthreads();

    // we[m][c] = omega[m][c>>3] * v[m][c];  write fp32 to d_out (scratch), BN partials
    float s = 0.f, ss = 0.f;
    float* wrow = weout + (size_t)t * MM * CC + c;
#pragma unroll
    for (int m = 0; m < MM; ++m) {
        float w = omg[m][c >> 3] * vreg[m];
        wrow[m * CC] = w;
        s += w; ss += w * w;
    }
    psum[(size_t)t * CC + c] = s;
    psq [(size_t)t * CC + c] = ss;
}

// ---------------------------------------------------------------------------
// Kernel 5: reduce per-block BN partials (16384 x 256) -> 256 sums
// ---------------------------------------------------------------------------
__global__ __launch_bounds__(256) void k_reduce_we(
    const float* __restrict__ psum, const float* __restrict__ psq,
    float* __restrict__ wsf)
{
    int c = threadIdx.x;
    int r0 = blockIdx.x * 64;
    float s = 0.f, ss = 0.f;
    for (int r = 0; r < 64; ++r) {
        s  += psum[(size_t)(r0 + r) * CC + c];
        ss += psq [(size_t)(r0 + r) * CC + c];
    }
    atomicAdd(&wsf[F_WESUM + c], s);
    atomicAdd(&wsf[F_WESQ  + c], ss);
}

// ---------------------------------------------------------------------------
// Kernel 6: finalize we-BN scale/shift
// ---------------------------------------------------------------------------
__global__ void k_finalize_we(const float* __restrict__ bng,
                              const float* __restrict__ bnb,
                              float* __restrict__ wsf)
{
    int c = threadIdx.x;
    float mean = wsf[F_WESUM + c] * (1.f / SAMP);
    float var  = wsf[F_WESQ  + c] * (1.f / SAMP) - mean * mean;
    float a = bng[c] * rsqrtf(var + EPSV);
    wsf[F_A_WE + c] = a;
    wsf[F_C_WE + c] = bnb[c] - mean * a;
}

// ---------------------------------------------------------------------------
// Kernel 7: out = relu(BN(we)) @ lin_w^T + lin_b, in-place on d_out.
// Each block stages its own 16 rows in LDS before overwriting them.
// ---------------------------------------------------------------------------
__global__ __launch_bounds__(256) void k_out(
    float* io,                               // d_out: read we, write result
    const float* __restrict__ wsf,
    const float* __restrict__ linw, const float* __restrict__ linb)
{
    __shared__ float hw[MM][CC];
    size_t t0 = (size_t)blockIdx.x * MM;     // 16 neighbour-token rows
    int c = threadIdx.x;
    float a = wsf[F_A_WE + c], sh = wsf[F_C_WE + c];
#pragma unroll
    for (int m = 0; m < MM; ++m) {
        float x = io[(t0 + m) * CC + c];
        hw[m][c] = fmaxf(0.f, x * a + sh);
    }
    __syncthreads();
    float acc[MM];
#pragma unroll
    for (int m = 0; m < MM; ++m) acc[m] = 0.f;
    const float4* wr = (const float4*)(linw + (size_t)c * CC);
    for (int i4 = 0; i4 < 64; ++i4) {
        float4 w = wr[i4];
#pragma unroll
        for (int m = 0; m < MM; ++m) {
            float4 h = *(const float4*)&hw[m][i4*4];
            acc[m] += h.x*w.x + h.y*w.y + h.z*w.z + h.w*w.w;
        }
    }
    float bo = linb[c];
#pragma unroll
    for (int m = 0; m < MM; ++m) io[(t0 + m) * CC + c] = acc[m] + bo;
}

// ---------------------------------------------------------------------------
extern "C" void kernel_launch(void* const* d_in, const int* in_sizes, int n_in,
                              void* d_out, int out_size, void* d_ws, size_t ws_size,
                              hipStream_t stream)
{
    (void)in_sizes; (void)n_in; (void)out_size; (void)ws_size;
    const float* pxyz = (const float*)d_in[0];
    const float* pf   = (const float*)d_in[1];
    const float* nxyz = (const float*)d_in[2];
    const float* nf   = (const float*)d_in[3];
    const float* mw1  = (const float*)d_in[4];
    const float* mb1  = (const float*)d_in[5];
    const float* mw2  = (const float*)d_in[6];
    const float* mb2  = (const float*)d_in[7];
    const float* mg   = (const float*)d_in[8];
    const float* mbe  = (const float*)d_in[9];
    const float* bw1  = (const float*)d_in[10];
    const float* bb1  = (const float*)d_in[11];
    const float* bw2  = (const float*)d_in[12];
    const float* bb2  = (const float*)d_in[13];
    const float* bg   = (const float*)d_in[14];
    const float* bbe  = (const float*)d_in[15];
    const float* qw   = (const float*)d_in[16];
    const float* qb   = (const float*)d_in[17];
    const float* kw   = (const float*)d_in[18];
    const float* kb   = (const float*)d_in[19];
    const float* vw   = (const float*)d_in[20];
    const float* vb   = (const float*)d_in[21];
    const float* cvw  = (const float*)d_in[22];
    const float* bng  = (const float*)d_in[23];
    const float* bnb  = (const float*)d_in[24];
    const float* lw   = (const float*)d_in[25];
    const float* lb   = (const float*)d_in[26];

    double* diffm = (double*)d_ws;
    float*  wsf   = (float*)d_ws;
    float*  qws   = (float*)((char*)d_ws + WS_Q_OFF);
    float*  psum  = (float*)((char*)d_ws + WS_PSUM_OFF);
    float*  psq   = (float*)((char*)d_ws + WS_PSQ_OFF);
    float*  out   = (float*)d_out;

    // zero the stats block (ws is poisoned 0xAA before every timed launch)
    hipMemsetAsync(d_ws, 0, 16384, stream);

    k_diff_stats<<<256, 256, 0, stream>>>(pxyz, nxyz, diffm);
    k_finalize_dmdb<<<1, 256, 0, stream>>>(diffm, mw1, mb1, mg, mbe,
                                           bw1, bb1, bg, bbe, wsf);
    k_q<<<TOK/8, 256, 0, stream>>>(pf, qw, qb, qws);
    k_main<<<TOK, 256, 0, stream>>>(pxyz, nxyz, nf,
                                    mw1, mb1, mw2, mb2,
                                    bw1, bb1, bw2, bb2,
                                    kw, kb, vw, vb, cvw,
                                    wsf, qws, out, psum, psq);
    k_reduce_we<<<256, 256, 0, stream>>>(psum, psq, wsf);
    k_finalize_we<<<1, 256, 0, stream>>>(bng, bnb, wsf);
    k_out<<<SAMP/16, 256, 0, stream>>>(out, wsf, lw, lb);
}

// Round 2
// 1423.568 us; speedup vs baseline: 4.1380x; 4.1380x over previous
//
#include <hip/hip_runtime.h>
#include <hip/hip_bf16.h>
#include <cstdint>
#include <cstddef>

// Problem constants
#define BB 4
#define NN 4096
#define MM 16
#define CC 256
#define TOK (BB*NN)        // 16384 (b,n) pairs
#define SAMP (TOK*MM)      // 262144 neighbour tokens
#define EPSV 1e-5f

typedef __attribute__((ext_vector_type(8))) short bf16x8;
typedef __attribute__((ext_vector_type(4))) float f32x4;

// ws float offsets (stats block, first 16KB)
#define F_A_DM 32
#define F_C_DM 288
#define F_A_DB 544
#define F_C_DB 800
#define F_WESUM 1056
#define F_WESQ 1312
#define F_A_WE 1568
#define F_C_WE 1824
// ws byte offsets
#define WS_WB_OFF 16384                       // 6 bf16 256x256 matrices, 128KB each
#define WS_Q_OFF   (WS_WB_OFF + 6*131072)     // float q[TOK*CC]
#define WS_PSUM_OFF (WS_Q_OFF + TOK*CC*4)
#define WS_PSQ_OFF  (WS_PSUM_OFF + TOK*CC*4)

// float -> bf16 round-to-nearest-even
__device__ __forceinline__ short f2bf(float f) {
    unsigned u = __builtin_bit_cast(unsigned, f);
    u += 0x7fffu + ((u >> 16) & 1u);
    return (short)(u >> 16);
}
__device__ __forceinline__ unsigned pack_bf(float lo, float hi) {
    return (unsigned)(unsigned short)f2bf(lo) | ((unsigned)(unsigned short)f2bf(hi) << 16);
}
__device__ __forceinline__ float bf2f(short s) {
    unsigned u = ((unsigned)(unsigned short)s) << 16;
    return __builtin_bit_cast(float, u);
}
// XOR-swizzled byte offset for a 256-col bf16 LDS row (row stride 512B).
// Spreads 16B slots of 8 consecutive rows across banks (G4 fix).
__device__ __forceinline__ int swz(int row, int byte_in_row) {
    return (row << 9) + (byte_in_row ^ ((row & 7) << 4));
}

// ---------------------------------------------------------------------------
// Kernel: convert 6 fp32 256x256 weight matrices to bf16 in ws
// ---------------------------------------------------------------------------
__global__ __launch_bounds__(256) void k_convert(
    const float* __restrict__ s0, const float* __restrict__ s1,
    const float* __restrict__ s2, const float* __restrict__ s3,
    const float* __restrict__ s4, const float* __restrict__ s5,
    short* __restrict__ dst)
{
    int mat = blockIdx.x >> 6;      // 64 blocks per matrix
    int i = blockIdx.x & 63;
    const float* s = (mat == 0) ? s0 : (mat == 1) ? s1 : (mat == 2) ? s2
                   : (mat == 3) ? s3 : (mat == 4) ? s4 : s5;
    int idx = i * 1024 + threadIdx.x * 4;
    float4 f = *(const float4*)(s + idx);
    uint2 o;
    o.x = pack_bf(f.x, f.y);
    o.y = pack_bf(f.z, f.w);
    *(uint2*)(dst + (size_t)mat * 65536 + idx) = o;
}

// ---------------------------------------------------------------------------
// Kernel: global moments of diff = p - nb (9 sums) for analytic BN stats
// ---------------------------------------------------------------------------
__global__ __launch_bounds__(256) void k_diff_stats(
    const float* __restrict__ pxyz, const float* __restrict__ nxyz,
    double* __restrict__ dst)
{
    int tid = blockIdx.x * 256 + threadIdx.x;
    int stride = gridDim.x * 256;
    float s[9];
#pragma unroll
    for (int j = 0; j < 9; ++j) s[j] = 0.f;
    for (int idx = tid; idx < SAMP; idx += stride) {
        int t = idx >> 4;
        float dx = pxyz[t*3+0] - nxyz[idx*3+0];
        float dy = pxyz[t*3+1] - nxyz[idx*3+1];
        float dz = pxyz[t*3+2] - nxyz[idx*3+2];
        s[0]+=dx; s[1]+=dy; s[2]+=dz;
        s[3]+=dx*dx; s[4]+=dx*dy; s[5]+=dx*dz;
        s[6]+=dy*dy; s[7]+=dy*dz; s[8]+=dz*dz;
    }
#pragma unroll
    for (int off = 32; off >= 1; off >>= 1) {
#pragma unroll
        for (int j = 0; j < 9; ++j) s[j] += __shfl_down(s[j], off, 64);
    }
    if ((threadIdx.x & 63) == 0) {
#pragma unroll
        for (int j = 0; j < 9; ++j) atomicAdd(&dst[j], (double)s[j]);
    }
}

// ---------------------------------------------------------------------------
// Kernel: analytic BN scale/shift for dm and db first-layer paths
// ---------------------------------------------------------------------------
__global__ void k_finalize_dmdb(
    const double* __restrict__ mom,
    const float* __restrict__ mw1, const float* __restrict__ mb1,
    const float* __restrict__ mg,  const float* __restrict__ mbe,
    const float* __restrict__ bw1, const float* __restrict__ bb1,
    const float* __restrict__ bg,  const float* __restrict__ bbe,
    float* __restrict__ wsf)
{
    int c = threadIdx.x;
    double inv = 1.0 / (double)SAMP;
    double Ex = mom[0]*inv, Ey = mom[1]*inv, Ez = mom[2]*inv;
    double Cxx = mom[3]*inv - Ex*Ex, Cxy = mom[4]*inv - Ex*Ey, Cxz = mom[5]*inv - Ex*Ez;
    double Cyy = mom[6]*inv - Ey*Ey, Cyz = mom[7]*inv - Ey*Ez, Czz = mom[8]*inv - Ez*Ez;
    {
        double w0 = mw1[c*3+0], w1 = mw1[c*3+1], w2 = mw1[c*3+2];
        double mu = w0*Ex + w1*Ey + w2*Ez + (double)mb1[c];
        double var = w0*w0*Cxx + w1*w1*Cyy + w2*w2*Czz
                   + 2.0*(w0*w1*Cxy + w0*w2*Cxz + w1*w2*Cyz);
        float a = mg[c] * rsqrtf((float)var + EPSV);
        wsf[F_A_DM + c] = a;
        wsf[F_C_DM + c] = mbe[c] - (float)mu * a;
    }
    {
        double w0 = bw1[c*3+0], w1 = bw1[c*3+1], w2 = bw1[c*3+2];
        double mu = w0*Ex + w1*Ey + w2*Ez + (double)bb1[c];
        double var = w0*w0*Cxx + w1*w1*Cyy + w2*w2*Czz
                   + 2.0*(w0*w1*Cxy + w0*w2*Cxz + w1*w2*Cyz);
        float a = bg[c] * rsqrtf((float)var + EPSV);
        wsf[F_A_DB + c] = a;
        wsf[F_C_DB + c] = bbe[c] - (float)mu * a;
    }
}

// ---------------------------------------------------------------------------
// Kernel: generic 64-row MFMA GEMM  out = x @ w^T + b   (used for q)
// ---------------------------------------------------------------------------
__global__ __launch_bounds__(256, 2) void k_gemm_rows(
    const float* __restrict__ x, const short* __restrict__ wb,
    const float* __restrict__ bias, float* __restrict__ out)
{
    __shared__ short s_a[64 * 256];
    const int tid = threadIdx.x;
    const int lane = tid & 63;
    const int wv = tid >> 6;
    const size_t r0 = (size_t)blockIdx.x * 64;

    {
        int c2 = (tid & 127) * 2;
#pragma unroll
        for (int i = 0; i < 32; ++i) {
            int r = (tid >> 7) + i * 2;
            float2 f = *(const float2*)(x + (r0 + r) * CC + c2);
            *(unsigned*)((char*)s_a + swz(r, c2 * 2)) = pack_bf(f.x, f.y);
        }
    }
    __syncthreads();

    f32x4 acc[16];
#pragma unroll
    for (int nt = 0; nt < 16; ++nt) acc[nt] = (f32x4){0.f, 0.f, 0.f, 0.f};
    const int mrow = wv * 16 + (lane & 15);
    for (int ks = 0; ks < 8; ++ks) {
        bf16x8 a = *(const bf16x8*)((char*)s_a + swz(mrow, (ks * 32 + (lane >> 4) * 8) * 2));
#pragma unroll
        for (int nt = 0; nt < 16; ++nt) {
            int col = nt * 16 + (lane & 15);
            bf16x8 b = *(const bf16x8*)(wb + (size_t)col * CC + ks * 32 + (lane >> 4) * 8);
            acc[nt] = __builtin_amdgcn_mfma_f32_16x16x32_bf16(a, b, acc[nt], 0, 0, 0);
        }
    }
#pragma unroll
    for (int nt = 0; nt < 16; ++nt) {
        int col = nt * 16 + (lane & 15);
        float bo = bias[col];
#pragma unroll
        for (int r = 0; r < 4; ++r) {
            size_t row = r0 + wv * 16 + (lane >> 4) * 4 + r;
            out[row * CC + col] = acc[nt][r] + bo;
        }
    }
}

// ---------------------------------------------------------------------------
// Main fused kernel: 2 tokens per block, 4 waves, each wave owns 64 N-cols.
// ---------------------------------------------------------------------------
__global__ __launch_bounds__(256, 2) void k_main(
    const float* __restrict__ pxyz, const float* __restrict__ nxyz,
    const float* __restrict__ nf,
    const float* __restrict__ mw1, const float* __restrict__ mb1,
    const float* __restrict__ mb2,
    const float* __restrict__ bw1, const float* __restrict__ bb1,
    const float* __restrict__ bb2,
    const float* __restrict__ kbv, const float* __restrict__ vbv,
    const float* __restrict__ convw,
    const float* __restrict__ wsf, const float* __restrict__ qws,
    const short* __restrict__ kwb, const short* __restrict__ vwb,
    const short* __restrict__ mwb, const short* __restrict__ bwb,
    float* __restrict__ weout, float* __restrict__ psum, float* __restrict__ psq)
{
    __shared__ short s_nf[2][MM * CC];   // nf tile (bf16, swizzled); reused for va after GEMM
    __shared__ short s_hm[2][MM * CC];
    __shared__ short s_hb[2][MM * CC];
    __shared__ float s_cwT[32 * 32];     // conv_w transposed: cwT[j][o]
    __shared__ float s_omg[2][MM * 32];
    __shared__ float s_dif[2][MM][4];

    const int tid = threadIdx.x;
    const int lane = tid & 63;
    const int wv = tid >> 6;
    const int t0 = blockIdx.x * 2;

    // ---- stage: cwT, dif, nf->bf16 swizzled ----
    {
        int j = tid >> 3, o0 = (tid & 7) * 4;
        float4 v;
        v.x = convw[(o0 + 0) * 32 + j];
        v.y = convw[(o0 + 1) * 32 + j];
        v.z = convw[(o0 + 2) * 32 + j];
        v.w = convw[(o0 + 3) * 32 + j];
        *(float4*)&s_cwT[j * 32 + o0] = v;
    }
    if (tid < 32) {
        int tok = tid >> 4, m = tid & 15;
        int t = t0 + tok;
        float px = pxyz[t*3+0], py = pxyz[t*3+1], pz = pxyz[t*3+2];
        const float* nx = nxyz + ((size_t)t * MM + m) * 3;
        s_dif[tok][m][0] = px - nx[0];
        s_dif[tok][m][1] = py - nx[1];
        s_dif[tok][m][2] = pz - nx[2];
    }
    {
        int c2 = (tid & 127) * 2;
        int rb = (tid >> 7) * 8;
#pragma unroll
        for (int tok = 0; tok < 2; ++tok) {
            const float* src = nf + (size_t)(t0 + tok) * MM * CC;
#pragma unroll
            for (int i = 0; i < 8; ++i) {
                int m = rb + i;
                float2 f = *(const float2*)(src + m * CC + c2);
                *(unsigned*)((char*)s_nf[tok] + swz(m, c2 * 2)) = pack_bf(f.x, f.y);
            }
        }
    }
    __syncthreads();

    // ---- h_dm / h_db: relu(analytic-BN(w1 . d + b1)) -> bf16 swizzled LDS ----
    {
        int c2 = (tid & 127) * 2;
        int rb = (tid >> 7) * 8;
        float w00 = mw1[c2*3+0], w01 = mw1[c2*3+1], w02 = mw1[c2*3+2];
        float w10 = mw1[c2*3+3], w11 = mw1[c2*3+4], w12 = mw1[c2*3+5];
        float mb0 = mb1[c2], mb1_ = mb1[c2+1];
        float ma0 = wsf[F_A_DM+c2], ma1 = wsf[F_A_DM+c2+1];
        float mc0 = wsf[F_C_DM+c2], mc1 = wsf[F_C_DM+c2+1];
        float u00 = bw1[c2*3+0], u01 = bw1[c2*3+1], u02 = bw1[c2*3+2];
        float u10 = bw1[c2*3+3], u11 = bw1[c2*3+4], u12 = bw1[c2*3+5];
        float eb0 = bb1[c2], eb1 = bb1[c2+1];
        float ea0 = wsf[F_A_DB+c2], ea1 = wsf[F_A_DB+c2+1];
        float ec0 = wsf[F_C_DB+c2], ec1 = wsf[F_C_DB+c2+1];
#pragma unroll
        for (int tok = 0; tok < 2; ++tok) {
#pragma unroll
            for (int i = 0; i < 8; ++i) {
                int m = rb + i;
                float d0 = s_dif[tok][m][0], d1 = s_dif[tok][m][1], d2 = s_dif[tok][m][2];
                float h0 = fmaxf(0.f, (w00*d0 + w01*d1 + w02*d2 + mb0) * ma0 + mc0);
                float h1 = fmaxf(0.f, (w10*d0 + w11*d1 + w12*d2 + mb1_) * ma1 + mc1);
                *(unsigned*)((char*)s_hm[tok] + swz(m, c2 * 2)) = pack_bf(h0, h1);
                float g0 = fmaxf(0.f, (u00*d0 + u01*d1 + u02*d2 + eb0) * ea0 + ec0);
                float g1 = fmaxf(0.f, (u10*d0 + u11*d1 + u12*d2 + eb1) * ea1 + ec1);
                *(unsigned*)((char*)s_hb[tok] + swz(m, c2 * 2)) = pack_bf(g0, g1);
            }
        }
    }
    __syncthreads();

    // ---- MFMA GEMMs: k, v, dm, db for this wave's 64-col N-quarter ----
    const int nb = wv * 64;
    f32x4 acc[4][4][2];   // [mat][nt][tok]
#pragma unroll
    for (int a = 0; a < 4; ++a)
#pragma unroll
        for (int b = 0; b < 4; ++b)
#pragma unroll
            for (int c = 0; c < 2; ++c) acc[a][b][c] = (f32x4){0.f, 0.f, 0.f, 0.f};

    const int arow = lane & 15;
    for (int ks = 0; ks < 8; ++ks) {
        const int abyte = (ks * 32 + (lane >> 4) * 8) * 2;
        bf16x8 a_nf0 = *(const bf16x8*)((char*)s_nf[0] + swz(arow, abyte));
        bf16x8 a_nf1 = *(const bf16x8*)((char*)s_nf[1] + swz(arow, abyte));
        bf16x8 a_hm0 = *(const bf16x8*)((char*)s_hm[0] + swz(arow, abyte));
        bf16x8 a_hm1 = *(const bf16x8*)((char*)s_hm[1] + swz(arow, abyte));
        bf16x8 a_hb0 = *(const bf16x8*)((char*)s_hb[0] + swz(arow, abyte));
        bf16x8 a_hb1 = *(const bf16x8*)((char*)s_hb[1] + swz(arow, abyte));
#pragma unroll
        for (int nt = 0; nt < 4; ++nt) {
            size_t boff = (size_t)(nb + nt * 16 + (lane & 15)) * CC + ks * 32 + (lane >> 4) * 8;
            bf16x8 b_k = *(const bf16x8*)(kwb + boff);
            acc[0][nt][0] = __builtin_amdgcn_mfma_f32_16x16x32_bf16(a_nf0, b_k, acc[0][nt][0], 0, 0, 0);
            acc[0][nt][1] = __builtin_amdgcn_mfma_f32_16x16x32_bf16(a_nf1, b_k, acc[0][nt][1], 0, 0, 0);
            bf16x8 b_v = *(const bf16x8*)(vwb + boff);
            acc[1][nt][0] = __builtin_amdgcn_mfma_f32_16x16x32_bf16(a_nf0, b_v, acc[1][nt][0], 0, 0, 0);
            acc[1][nt][1] = __builtin_amdgcn_mfma_f32_16x16x32_bf16(a_nf1, b_v, acc[1][nt][1], 0, 0, 0);
            bf16x8 b_m = *(const bf16x8*)(mwb + boff);
            acc[2][nt][0] = __builtin_amdgcn_mfma_f32_16x16x32_bf16(a_hm0, b_m, acc[2][nt][0], 0, 0, 0);
            acc[2][nt][1] = __builtin_amdgcn_mfma_f32_16x16x32_bf16(a_hm1, b_m, acc[2][nt][1], 0, 0, 0);
            bf16x8 b_b = *(const bf16x8*)(bwb + boff);
            acc[3][nt][0] = __builtin_amdgcn_mfma_f32_16x16x32_bf16(a_hb0, b_b, acc[3][nt][0], 0, 0, 0);
            acc[3][nt][1] = __builtin_amdgcn_mfma_f32_16x16x32_bf16(a_hb1, b_b, acc[3][nt][1], 0, 0, 0);
        }
    }
    __syncthreads();   // all A-reads done; s_nf becomes va storage

    // ---- va = dm*(q-k)+db -> bf16 swizzled LDS (aliases s_nf) ----
#pragma unroll
    for (int tok = 0; tok < 2; ++tok) {
#pragma unroll
        for (int nt = 0; nt < 4; ++nt) {
            int col = nb + nt * 16 + (lane & 15);
            float qv = qws[(size_t)(t0 + tok) * CC + col];
            float kbc = kbv[col], mbc = mb2[col], bbc = bb2[col];
#pragma unroll
            for (int r = 0; r < 4; ++r) {
                float kk = acc[0][nt][tok][r] + kbc;
                float dmv = acc[2][nt][tok][r] + mbc;
                float dbv = acc[3][nt][tok][r] + bbc;
                float va = dmv * (qv - kk) + dbv;
                int row = (lane >> 4) * 4 + r;
                *(short*)((char*)s_nf[tok] + swz(row, col * 2)) = f2bf(va);
            }
        }
    }
    __syncthreads();

    // ---- grouped conv: omega[tok][m][o] ----
    {
        int pair = tid >> 3;          // 0..31 -> (tok, m)
        int tok = pair >> 4, m = pair & 15;
        int s = tid & 7;              // group g = s, outputs o = s*4 .. s*4+3
        float vav[32];
#pragma unroll
        for (int u = 0; u < 4; ++u) {
            bf16x8 ch = *(const bf16x8*)((char*)s_nf[tok] + swz(m, (s * 32 + u * 8) * 2));
#pragma unroll
            for (int j = 0; j < 8; ++j) vav[u * 8 + j] = bf2f(ch[j]);
        }
        int o0 = s * 4;
        float oa0 = 0.f, oa1 = 0.f, oa2 = 0.f, oa3 = 0.f;
#pragma unroll
        for (int j = 0; j < 32; ++j) {
            float4 w = *(const float4*)&s_cwT[j * 32 + o0];
            float a = vav[j];
            oa0 += a * w.x; oa1 += a * w.y; oa2 += a * w.z; oa3 += a * w.w;
        }
        *(float4*)&s_omg[tok][m * 32 + o0] = make_float4(oa0, oa1, oa2, oa3);
    }
    __syncthreads();

    // ---- softmax over 32 outputs, 8 lanes per (tok,m) row ----
    {
        int rr = tid >> 3;
        int tok = rr >> 4, m = rr & 15;
        int s = tid & 7;
        float4 x = *(const float4*)&s_omg[tok][m * 32 + s * 4];
        float mx = fmaxf(fmaxf(x.x, x.y), fmaxf(x.z, x.w));
#pragma unroll
        for (int d = 1; d < 8; d <<= 1) mx = fmaxf(mx, __shfl_xor(mx, d));
        float e0 = __expf(x.x - mx), e1 = __expf(x.y - mx);
        float e2 = __expf(x.z - mx), e3 = __expf(x.w - mx);
        float sm = e0 + e1 + e2 + e3;
#pragma unroll
        for (int d = 1; d < 8; d <<= 1) sm += __shfl_xor(sm, d);
        float inv = 1.f / sm;
        *(float4*)&s_omg[tok][m * 32 + s * 4] = make_float4(e0 * inv, e1 * inv, e2 * inv, e3 * inv);
    }
    __syncthreads();

    // ---- we = omega * v : write fp32 to d_out scratch + BN partials ----
#pragma unroll
    for (int tok = 0; tok < 2; ++tok) {
        int t = t0 + tok;
#pragma unroll
        for (int nt = 0; nt < 4; ++nt) {
            int col = nb + nt * 16 + (lane & 15);
            float vbc = vbv[col];
            float s = 0.f, ss = 0.f;
#pragma unroll
            for (int r = 0; r < 4; ++r) {
                int row = (lane >> 4) * 4 + r;
                float w = s_omg[tok][row * 32 + (col >> 3)] * (acc[1][nt][tok][r] + vbc);
                weout[((size_t)t * MM + row) * CC + col] = w;
                s += w; ss += w * w;
            }
            s += __shfl_xor(s, 16);  s += __shfl_xor(s, 32);
            ss += __shfl_xor(ss, 16); ss += __shfl_xor(ss, 32);
            if (lane < 16) {
                psum[(size_t)t * CC + col] = s;
                psq [(size_t)t * CC + col] = ss;
            }
        }
    }
}

// ---------------------------------------------------------------------------
// Kernel: reduce per-token BN partials -> 256 channel sums
// ---------------------------------------------------------------------------
__global__ __launch_bounds__(256) void k_reduce_we(
    const float* __restrict__ psum, const float* __restrict__ psq,
    float* __restrict__ wsf)
{
    int c = threadIdx.x;
    int r0 = blockIdx.x * 64;
    float s = 0.f, ss = 0.f;
    for (int r = 0; r < 64; ++r) {
        s  += psum[(size_t)(r0 + r) * CC + c];
        ss += psq [(size_t)(r0 + r) * CC + c];
    }
    atomicAdd(&wsf[F_WESUM + c], s);
    atomicAdd(&wsf[F_WESQ  + c], ss);
}

__global__ void k_finalize_we(const float* __restrict__ bng,
                              const float* __restrict__ bnb,
                              float* __restrict__ wsf)
{
    int c = threadIdx.x;
    float mean = wsf[F_WESUM + c] * (1.f / SAMP);
    float var  = wsf[F_WESQ  + c] * (1.f / SAMP) - mean * mean;
    float a = bng[c] * rsqrtf(var + EPSV);
    wsf[F_A_WE + c] = a;
    wsf[F_C_WE + c] = bnb[c] - mean * a;
}

// ---------------------------------------------------------------------------
// Kernel: out = relu(BN(we)) @ lin_w^T + lin_b, in-place on d_out (MFMA)
// ---------------------------------------------------------------------------
__global__ __launch_bounds__(256, 2) void k_out(
    float* io, const float* __restrict__ wsf,
    const short* __restrict__ lwb, const float* __restrict__ linb)
{
    __shared__ short s_a[64 * 256];
    const int tid = threadIdx.x;
    const int lane = tid & 63;
    const int wv = tid >> 6;
    const size_t r0 = (size_t)blockIdx.x * 64;

    {
        int c2 = (tid & 127) * 2;
        float a0 = wsf[F_A_WE + c2], sh0 = wsf[F_C_WE + c2];
        float a1 = wsf[F_A_WE + c2 + 1], sh1 = wsf[F_C_WE + c2 + 1];
#pragma unroll
        for (int i = 0; i < 32; ++i) {
            int r = (tid >> 7) + i * 2;
            float2 f = *(const float2*)(io + (r0 + r) * CC + c2);
            float h0 = fmaxf(0.f, f.x * a0 + sh0);
            float h1 = fmaxf(0.f, f.y * a1 + sh1);
            *(unsigned*)((char*)s_a + swz(r, c2 * 2)) = pack_bf(h0, h1);
        }
    }
    __syncthreads();

    f32x4 acc[16];
#pragma unroll
    for (int nt = 0; nt < 16; ++nt) acc[nt] = (f32x4){0.f, 0.f, 0.f, 0.f};
    const int mrow = wv * 16 + (lane & 15);
    for (int ks = 0; ks < 8; ++ks) {
        bf16x8 a = *(const bf16x8*)((char*)s_a + swz(mrow, (ks * 32 + (lane >> 4) * 8) * 2));
#pragma unroll
        for (int nt = 0; nt < 16; ++nt) {
            int col = nt * 16 + (lane & 15);
            bf16x8 b = *(const bf16x8*)(lwb + (size_t)col * CC + ks * 32 + (lane >> 4) * 8);
            acc[nt] = __builtin_amdgcn_mfma_f32_16x16x32_bf16(a, b, acc[nt], 0, 0, 0);
        }
    }
#pragma unroll
    for (int nt = 0; nt < 16; ++nt) {
        int col = nt * 16 + (lane & 15);
        float bo = linb[col];
#pragma unroll
        for (int r = 0; r < 4; ++r) {
            size_t row = r0 + wv * 16 + (lane >> 4) * 4 + r;
            io[row * CC + col] = acc[nt][r] + bo;
        }
    }
}

// ---------------------------------------------------------------------------
extern "C" void kernel_launch(void* const* d_in, const int* in_sizes, int n_in,
                              void* d_out, int out_size, void* d_ws, size_t ws_size,
                              hipStream_t stream)
{
    (void)in_sizes; (void)n_in; (void)out_size; (void)ws_size;
    const float* pxyz = (const float*)d_in[0];
    const float* pf   = (const float*)d_in[1];
    const float* nxyz = (const float*)d_in[2];
    const float* nf   = (const float*)d_in[3];
    const float* mw1  = (const float*)d_in[4];
    const float* mb1  = (const float*)d_in[5];
    const float* mw2  = (const float*)d_in[6];
    const float* mb2  = (const float*)d_in[7];
    const float* mg   = (const float*)d_in[8];
    const float* mbe  = (const float*)d_in[9];
    const float* bw1  = (const float*)d_in[10];
    const float* bb1  = (const float*)d_in[11];
    const float* bw2  = (const float*)d_in[12];
    const float* bb2  = (const float*)d_in[13];
    const float* bg   = (const float*)d_in[14];
    const float* bbe  = (const float*)d_in[15];
    const float* qw   = (const float*)d_in[16];
    const float* qb   = (const float*)d_in[17];
    const float* kw   = (const float*)d_in[18];
    const float* kb   = (const float*)d_in[19];
    const float* vw   = (const float*)d_in[20];
    const float* vb   = (const float*)d_in[21];
    const float* cvw  = (const float*)d_in[22];
    const float* bng  = (const float*)d_in[23];
    const float* bnb  = (const float*)d_in[24];
    const float* lw   = (const float*)d_in[25];
    const float* lb   = (const float*)d_in[26];

    double* diffm = (double*)d_ws;
    float*  wsf   = (float*)d_ws;
    short*  wbase = (short*)((char*)d_ws + WS_WB_OFF);
    short*  kwb   = wbase + 0 * 65536;
    short*  vwb   = wbase + 1 * 65536;
    short*  mwb   = wbase + 2 * 65536;
    short*  bwb   = wbase + 3 * 65536;
    short*  qwb   = wbase + 4 * 65536;
    short*  lwb   = wbase + 5 * 65536;
    float*  qws   = (float*)((char*)d_ws + WS_Q_OFF);
    float*  psum  = (float*)((char*)d_ws + WS_PSUM_OFF);
    float*  psq   = (float*)((char*)d_ws + WS_PSQ_OFF);
    float*  out   = (float*)d_out;

    hipMemsetAsync(d_ws, 0, 16384, stream);

    k_convert<<<384, 256, 0, stream>>>(kw, vw, mw2, bw2, qw, lw, wbase);
    k_diff_stats<<<256, 256, 0, stream>>>(pxyz, nxyz, diffm);
    k_finalize_dmdb<<<1, 256, 0, stream>>>(diffm, mw1, mb1, mg, mbe,
                                           bw1, bb1, bg, bbe, wsf);
    k_gemm_rows<<<TOK / 64, 256, 0, stream>>>(pf, qwb, qb, qws);
    k_main<<<TOK / 2, 256, 0, stream>>>(pxyz, nxyz, nf,
                                        mw1, mb1, mb2,
                                        bw1, bb1, bb2,
                                        kb, vb, cvw,
                                        wsf, qws,
                                        kwb, vwb, mwb, bwb,
                                        out, psum, psq);
    k_reduce_we<<<256, 256, 0, stream>>>(psum, psq, wsf);
    k_finalize_we<<<1, 256, 0, stream>>>(bng, bnb, wsf);
    k_out<<<SAMP / 64, 256, 0, stream>>>(out, wsf, lwb, lb);
}